// Round 1
// baseline (2819.512 us; speedup 1.0000x reference)
//
#include <hip/hip_runtime.h>

#define HID 128

__global__ __launch_bounds__(256) void k_count_deg(const int* __restrict__ dst, int* __restrict__ deg, int E){
  int e = blockIdx.x*256 + threadIdx.x;
  if (e < E) atomicAdd(&deg[dst[e]], 1);
}

__global__ __launch_bounds__(256) void k_dinv(const int* __restrict__ deg, float* __restrict__ dinv, int N){
  int n = blockIdx.x*256 + threadIdx.x;
  if (n < N){
    int d = deg[n];
    dinv[n] = d > 0 ? rsqrtf((float)d) : 0.0f;
  }
}

// Per-block inclusive scan of deg, one atomic bump of a global cursor per block.
// Row ranges are disjoint; cross-block ordering is irrelevant to per-node sums.
__global__ __launch_bounds__(256) void k_alloc(const int* __restrict__ deg, int* __restrict__ rowstart,
                                               int* __restrict__ cursor, int N){
  __shared__ int sm[256];
  __shared__ int sbase;
  int t = threadIdx.x;
  int n = blockIdx.x*256 + t;
  int d = (n < N) ? deg[n] : 0;
  sm[t] = d;
  __syncthreads();
  for (int off = 1; off < 256; off <<= 1){
    int v = (t >= off) ? sm[t-off] : 0;
    __syncthreads();
    sm[t] += v;
    __syncthreads();
  }
  if (t == 255) sbase = atomicAdd(cursor, sm[255]);
  __syncthreads();
  if (n < N) rowstart[n] = sbase + sm[t] - d;   // exclusive within block + block base
}

__global__ __launch_bounds__(256) void k_fill(const int* __restrict__ src, const int* __restrict__ dst,
                                              const float* __restrict__ dinv, const int* __restrict__ rowstart,
                                              int* __restrict__ fill, int2* __restrict__ slots, int E){
  int e = blockIdx.x*256 + threadIdx.x;
  if (e >= E) return;
  int s = src[e], d = dst[e];
  int p = atomicAdd(&fill[d], 1);
  float w = dinv[s]*dinv[d];
  slots[rowstart[d] + p] = make_int2(s, __float_as_int(w));
}

// H[r] = X[r] @ W  ;  W (64KB) fully in LDS, 32-row X tile in LDS,
// per-thread 4 rows x 4 cols register block -> VALU-bound.
__global__ __launch_bounds__(256) void k_gemm(const float* __restrict__ X, const float* __restrict__ W,
                                              float* __restrict__ H, int N){
  __shared__ float sW[HID*HID];   // 64 KB
  __shared__ float sX[32*HID];    // 16 KB
  int t = threadIdx.x;
  const float4* W4 = (const float4*)W;
  float4* sW4 = (float4*)sW;
#pragma unroll
  for (int i = 0; i < 16; i++) sW4[t + 256*i] = W4[t + 256*i];
  int row0 = blockIdx.x * 32;
  float4* sX4 = (float4*)sX;
#pragma unroll
  for (int i = 0; i < 4; i++){
    int idx = t + 256*i;                 // float4 index in tile; 32 per row
    int r = row0 + (idx >> 5);
    float4 v = make_float4(0.f,0.f,0.f,0.f);
    if (r < N) v = *(const float4*)(X + (size_t)r*HID + (size_t)(idx & 31)*4);
    sX4[idx] = v;
  }
  __syncthreads();
  int tx = t & 31, ty = t >> 5;
  float acc[4][4] = {};
  const float* xs = sX + ty*4*HID;
#pragma unroll
  for (int k = 0; k < HID; k += 4){
    float4 wv[4];
#pragma unroll
    for (int kk = 0; kk < 4; kk++) wv[kk] = *(const float4*)(sW + (size_t)(k+kk)*HID + tx*4);
#pragma unroll
    for (int r = 0; r < 4; r++){
      float4 xv = *(const float4*)(xs + r*HID + k);
      float xk[4] = {xv.x, xv.y, xv.z, xv.w};
#pragma unroll
      for (int kk = 0; kk < 4; kk++){
        acc[r][0] += xk[kk]*wv[kk].x;
        acc[r][1] += xk[kk]*wv[kk].y;
        acc[r][2] += xk[kk]*wv[kk].z;
        acc[r][3] += xk[kk]*wv[kk].w;
      }
    }
  }
#pragma unroll
  for (int r = 0; r < 4; r++){
    int row = row0 + ty*4 + r;
    if (row < N)
      *(float4*)(H + (size_t)row*HID + tx*4) = make_float4(acc[r][0],acc[r][1],acc[r][2],acc[r][3]);
  }
}

// One wave per node; lanes hold float2 of the 128-wide row; serial loop over in-edges.
__global__ __launch_bounds__(256) void k_agg(const float* __restrict__ H, const int2* __restrict__ slots,
                                             const int* __restrict__ rowstart, const int* __restrict__ deg,
                                             const float* __restrict__ bias, float* __restrict__ out, int N){
  int wid = threadIdx.x >> 6, lane = threadIdx.x & 63;
  int n = blockIdx.x*4 + wid;
  if (n >= N) return;
  int st = rowstart[n], cnt = deg[n];
  float a0 = 0.f, a1 = 0.f;
  for (int j = 0; j < cnt; j++){
    int2 sl = slots[st + j];
    float w = __int_as_float(sl.y);
    float2 hv = *(const float2*)(H + (size_t)sl.x*HID + lane*2);
    a0 += w*hv.x; a1 += w*hv.y;
  }
  float2 b = *(const float2*)(bias + lane*2);
  float2 o; o.x = a0 + b.x; o.y = a1 + b.y;
  *(float2*)(out + (size_t)n*HID + lane*2) = o;
}

extern "C" void kernel_launch(void* const* d_in, const int* in_sizes, int n_in,
                              void* d_out, int out_size, void* d_ws, size_t ws_size,
                              hipStream_t stream){
  const float* x  = (const float*)d_in[0];
  const int*   ei = (const int*)d_in[1];
  const float* Ws = (const float*)d_in[2];
  const float* bs = (const float*)d_in[3];
  const int N = in_sizes[0] / HID;
  const int E = in_sizes[1] / 2;
  const int L = in_sizes[2] / (HID*HID);
  const int* src = ei;        // edge_index[0]
  const int* dst = ei + E;    // edge_index[1]

  char* w = (char*)d_ws;
  int*   deg      = (int*)w;   w += (size_t)N*4;
  int*   fill     = (int*)w;   w += (size_t)N*4;
  int*   cursor   = (int*)w;   w += 16;
  size_t zbytes = (size_t)(w - (char*)d_ws);       // deg + fill + cursor must be zeroed
  float* dinv     = (float*)w; w += (size_t)N*4;
  int*   rowstart = (int*)w;   w += (size_t)N*4;
  int2*  slots    = (int2*)w;  w += (size_t)E*8;
  float* h        = (float*)w; w += (size_t)N*HID*4;

  hipMemsetAsync(d_ws, 0, zbytes, stream);

  int gE = (E + 255)/256, gN = (N + 255)/256;
  k_count_deg<<<gE, 256, 0, stream>>>(dst, deg, E);
  k_dinv    <<<gN, 256, 0, stream>>>(deg, dinv, N);
  k_alloc   <<<gN, 256, 0, stream>>>(deg, rowstart, cursor, N);
  k_fill    <<<gE, 256, 0, stream>>>(src, dst, dinv, rowstart, fill, slots, E);

  const float* xin = x;
  float* out = (float*)d_out;
  for (int l = 0; l < L; l++){
    k_gemm<<<(N + 31)/32, 256, 0, stream>>>(xin, Ws + (size_t)l*HID*HID, h, N);
    k_agg <<<(N + 3)/4,  256, 0, stream>>>(h, slots, rowstart, deg, bs + (size_t)l*HID, out, N);
    xin = out;
  }
}

// Round 2
// 614.563 us; speedup vs baseline: 4.5878x; 4.5878x over previous
//
#include <hip/hip_runtime.h>

#define HID 128

__global__ __launch_bounds__(256) void k_count_deg(const int* __restrict__ dst, int* __restrict__ deg, int E){
  int e = blockIdx.x*256 + threadIdx.x;
  if (e < E) atomicAdd(&deg[dst[e]], 1);
}

__global__ __launch_bounds__(256) void k_dinv(const int* __restrict__ deg, float* __restrict__ dinv, int N){
  int n = blockIdx.x*256 + threadIdx.x;
  if (n < N){
    int d = deg[n];
    dinv[n] = d > 0 ? rsqrtf((float)d) : 0.0f;
  }
}

// Per-block inclusive scan of deg, one atomic bump of a global cursor per block.
__global__ __launch_bounds__(256) void k_alloc(const int* __restrict__ deg, int* __restrict__ rowstart,
                                               int* __restrict__ cursor, int N){
  __shared__ int sm[256];
  __shared__ int sbase;
  int t = threadIdx.x;
  int n = blockIdx.x*256 + t;
  int d = (n < N) ? deg[n] : 0;
  sm[t] = d;
  __syncthreads();
  for (int off = 1; off < 256; off <<= 1){
    int v = (t >= off) ? sm[t-off] : 0;
    __syncthreads();
    sm[t] += v;
    __syncthreads();
  }
  if (t == 255) sbase = atomicAdd(cursor, sm[255]);
  __syncthreads();
  if (n < N) rowstart[n] = sbase + sm[t] - d;
}

__global__ __launch_bounds__(256) void k_fill(const int* __restrict__ src, const int* __restrict__ dst,
                                              const float* __restrict__ dinv, const int* __restrict__ rowstart,
                                              int* __restrict__ fill, int2* __restrict__ slots, int E){
  int e = blockIdx.x*256 + threadIdx.x;
  if (e >= E) return;
  int s = src[e], d = dst[e];
  int p = atomicAdd(&fill[d], 1);
  float w = dinv[s]*dinv[d];
  slots[rowstart[d] + p] = make_int2(s, __float_as_int(w));
}

// H[r] = X[r] @ W ; W (64KB) in LDS, 32-row X tile in LDS,
// per-thread 4 rows x 4 cols register block.
// k-loop unroll BOUNDED to 2: full unroll caused 256-VGPR blowout + 1.35GB
// scratch spill traffic (R1 rocprof: VALUBusy 4%, 3.3GB HBM/dispatch).
__global__ __launch_bounds__(256) void k_gemm(const float* __restrict__ X, const float* __restrict__ W,
                                              float* __restrict__ H, int N){
  __shared__ float sW[HID*HID];   // 64 KB
  __shared__ float sX[32*HID];    // 16 KB
  int t = threadIdx.x;
  const float4* W4 = (const float4*)W;
  float4* sW4 = (float4*)sW;
#pragma unroll
  for (int i = 0; i < 16; i++) sW4[t + 256*i] = W4[t + 256*i];
  int row0 = blockIdx.x * 32;
  float4* sX4 = (float4*)sX;
#pragma unroll
  for (int i = 0; i < 4; i++){
    int idx = t + 256*i;                 // float4 index in tile; 32 per row
    int r = row0 + (idx >> 5);
    float4 v = make_float4(0.f,0.f,0.f,0.f);
    if (r < N) v = *(const float4*)(X + (size_t)r*HID + (size_t)(idx & 31)*4);
    sX4[idx] = v;
  }
  __syncthreads();
  int tx = t & 31, ty = t >> 5;
  float acc[4][4] = {};
  const float* xs = sX + ty*4*HID;
#pragma unroll 2
  for (int k = 0; k < HID; k += 4){
    float4 wv[4];
#pragma unroll
    for (int kk = 0; kk < 4; kk++) wv[kk] = *(const float4*)(sW + (size_t)(k+kk)*HID + tx*4);
#pragma unroll
    for (int r = 0; r < 4; r++){
      float4 xv = *(const float4*)(xs + r*HID + k);
      float xk[4] = {xv.x, xv.y, xv.z, xv.w};
#pragma unroll
      for (int kk = 0; kk < 4; kk++){
        acc[r][0] += xk[kk]*wv[kk].x;
        acc[r][1] += xk[kk]*wv[kk].y;
        acc[r][2] += xk[kk]*wv[kk].z;
        acc[r][3] += xk[kk]*wv[kk].w;
      }
    }
  }
#pragma unroll
  for (int r = 0; r < 4; r++){
    int row = row0 + ty*4 + r;
    if (row < N)
      *(float4*)(H + (size_t)row*HID + tx*4) = make_float4(acc[r][0],acc[r][1],acc[r][2],acc[r][3]);
  }
}

// One wave per node; lanes hold float2 of the 128-wide row; serial loop over in-edges.
__global__ __launch_bounds__(256) void k_agg(const float* __restrict__ H, const int2* __restrict__ slots,
                                             const int* __restrict__ rowstart, const int* __restrict__ deg,
                                             const float* __restrict__ bias, float* __restrict__ out, int N){
  int wid = threadIdx.x >> 6, lane = threadIdx.x & 63;
  int n = blockIdx.x*4 + wid;
  if (n >= N) return;
  int st = rowstart[n], cnt = deg[n];
  float a0 = 0.f, a1 = 0.f;
  for (int j = 0; j < cnt; j++){
    int2 sl = slots[st + j];
    float w = __int_as_float(sl.y);
    float2 hv = *(const float2*)(H + (size_t)sl.x*HID + lane*2);
    a0 += w*hv.x; a1 += w*hv.y;
  }
  float2 b = *(const float2*)(bias + lane*2);
  float2 o; o.x = a0 + b.x; o.y = a1 + b.y;
  *(float2*)(out + (size_t)n*HID + lane*2) = o;
}

extern "C" void kernel_launch(void* const* d_in, const int* in_sizes, int n_in,
                              void* d_out, int out_size, void* d_ws, size_t ws_size,
                              hipStream_t stream){
  const float* x  = (const float*)d_in[0];
  const int*   ei = (const int*)d_in[1];
  const float* Ws = (const float*)d_in[2];
  const float* bs = (const float*)d_in[3];
  const int N = in_sizes[0] / HID;
  const int E = in_sizes[1] / 2;
  const int L = in_sizes[2] / (HID*HID);
  const int* src = ei;        // edge_index[0]
  const int* dst = ei + E;    // edge_index[1]

  char* w = (char*)d_ws;
  int*   deg      = (int*)w;   w += (size_t)N*4;
  int*   fill     = (int*)w;   w += (size_t)N*4;
  int*   cursor   = (int*)w;   w += 16;
  size_t zbytes = (size_t)(w - (char*)d_ws);       // deg + fill + cursor must be zeroed
  float* dinv     = (float*)w; w += (size_t)N*4;
  int*   rowstart = (int*)w;   w += (size_t)N*4;
  int2*  slots    = (int2*)w;  w += (size_t)E*8;
  float* h        = (float*)w; w += (size_t)N*HID*4;

  hipMemsetAsync(d_ws, 0, zbytes, stream);

  int gE = (E + 255)/256, gN = (N + 255)/256;
  k_count_deg<<<gE, 256, 0, stream>>>(dst, deg, E);
  k_dinv    <<<gN, 256, 0, stream>>>(deg, dinv, N);
  k_alloc   <<<gN, 256, 0, stream>>>(deg, rowstart, cursor, N);
  k_fill    <<<gE, 256, 0, stream>>>(src, dst, dinv, rowstart, fill, slots, E);

  const float* xin = x;
  float* out = (float*)d_out;
  for (int l = 0; l < L; l++){
    k_gemm<<<(N + 31)/32, 256, 0, stream>>>(xin, Ws + (size_t)l*HID*HID, h, N);
    k_agg <<<(N + 3)/4,  256, 0, stream>>>(h, slots, rowstart, deg, bs + (size_t)l*HID, out, N);
    xin = out;
  }
}

// Round 3
// 538.219 us; speedup vs baseline: 5.2386x; 1.1418x over previous
//
#include <hip/hip_runtime.h>

#define HID 128

__global__ __launch_bounds__(256) void k_count_deg(const int* __restrict__ dst, int* __restrict__ deg, int E){
  int e = blockIdx.x*256 + threadIdx.x;
  if (e < E) atomicAdd(&deg[dst[e]], 1);
}

// Per-block inclusive scan of deg, one atomic bump of a global cursor per block.
// Also emits dinv (fused, saves a launch).
__global__ __launch_bounds__(256) void k_alloc(const int* __restrict__ deg, int* __restrict__ rowstart,
                                               float* __restrict__ dinv, int* __restrict__ cursor, int N){
  __shared__ int sm[256];
  __shared__ int sbase;
  int t = threadIdx.x;
  int n = blockIdx.x*256 + t;
  int d = (n < N) ? deg[n] : 0;
  sm[t] = d;
  __syncthreads();
  for (int off = 1; off < 256; off <<= 1){
    int v = (t >= off) ? sm[t-off] : 0;
    __syncthreads();
    sm[t] += v;
    __syncthreads();
  }
  if (t == 255) sbase = atomicAdd(cursor, sm[255]);
  __syncthreads();
  if (n < N){
    rowstart[n] = sbase + sm[t] - d;
    dinv[n] = d > 0 ? rsqrtf((float)d) : 0.0f;
  }
}

__global__ __launch_bounds__(256) void k_fill(const int* __restrict__ src, const int* __restrict__ dst,
                                              const float* __restrict__ dinv, const int* __restrict__ rowstart,
                                              int* __restrict__ fill, int2* __restrict__ slots, int E){
  int e = blockIdx.x*256 + threadIdx.x;
  if (e >= E) return;
  int s = src[e], d = dst[e];
  int p = atomicAdd(&fill[d], 1);
  float w = dinv[s]*dinv[d];
  slots[rowstart[d] + p] = make_int2(s, __float_as_int(w));
}

// H[r] = X[r] @ W ; W (64KB) in LDS, 32-row X tile in LDS,
// per-thread 4 rows x 4 cols register block.
// k-loop unroll BOUNDED to 2: full unroll caused 256-VGPR blowout + 1.35GB
// scratch spill traffic (R1 rocprof: VALUBusy 4%, 3.3GB HBM/dispatch).
__global__ __launch_bounds__(256) void k_gemm(const float* __restrict__ X, const float* __restrict__ W,
                                              float* __restrict__ H, int N){
  __shared__ float sW[HID*HID];   // 64 KB
  __shared__ float sX[32*HID];    // 16 KB
  int t = threadIdx.x;
  const float4* W4 = (const float4*)W;
  float4* sW4 = (float4*)sW;
#pragma unroll
  for (int i = 0; i < 16; i++) sW4[t + 256*i] = W4[t + 256*i];
  int row0 = blockIdx.x * 32;
  float4* sX4 = (float4*)sX;
#pragma unroll
  for (int i = 0; i < 4; i++){
    int idx = t + 256*i;                 // float4 index in tile; 32 per row
    int r = row0 + (idx >> 5);
    float4 v = make_float4(0.f,0.f,0.f,0.f);
    if (r < N) v = *(const float4*)(X + (size_t)r*HID + (size_t)(idx & 31)*4);
    sX4[idx] = v;
  }
  __syncthreads();
  int tx = t & 31, ty = t >> 5;
  float acc[4][4] = {};
  const float* xs = sX + ty*4*HID;
#pragma unroll 2
  for (int k = 0; k < HID; k += 4){
    float4 wv[4];
#pragma unroll
    for (int kk = 0; kk < 4; kk++) wv[kk] = *(const float4*)(sW + (size_t)(k+kk)*HID + tx*4);
#pragma unroll
    for (int r = 0; r < 4; r++){
      float4 xv = *(const float4*)(xs + r*HID + k);
      float xk[4] = {xv.x, xv.y, xv.z, xv.w};
#pragma unroll
      for (int kk = 0; kk < 4; kk++){
        acc[r][0] += xk[kk]*wv[kk].x;
        acc[r][1] += xk[kk]*wv[kk].y;
        acc[r][2] += xk[kk]*wv[kk].z;
        acc[r][3] += xk[kk]*wv[kk].w;
      }
    }
  }
#pragma unroll
  for (int r = 0; r < 4; r++){
    int row = row0 + ty*4 + r;
    if (row < N)
      *(float4*)(H + (size_t)row*HID + tx*4) = make_float4(acc[r][0],acc[r][1],acc[r][2],acc[r][3]);
  }
}

// One wave per node; lanes hold float2 of the 128-wide row.
// Edge loop unrolled 4x: 4 independent slot loads then 4 independent row
// gathers in flight per wave (R2: 1-deep chain was latency-bound at 3 TB/s,
// VALUBusy 14%).
__global__ __launch_bounds__(256) void k_agg(const float* __restrict__ H, const int2* __restrict__ slots,
                                             const int* __restrict__ rowstart, const int* __restrict__ deg,
                                             const float* __restrict__ bias, float* __restrict__ out, int N){
  int wid = threadIdx.x >> 6, lane = threadIdx.x & 63;
  int n = blockIdx.x*4 + wid;
  if (n >= N) return;
  int st = rowstart[n], cnt = deg[n];
  float a0 = 0.f, a1 = 0.f;
  int j = 0;
  for (; j + 4 <= cnt; j += 4){
    int2 s0 = slots[st+j+0];
    int2 s1 = slots[st+j+1];
    int2 s2 = slots[st+j+2];
    int2 s3 = slots[st+j+3];
    float2 h0 = *(const float2*)(H + (size_t)s0.x*HID + lane*2);
    float2 h1 = *(const float2*)(H + (size_t)s1.x*HID + lane*2);
    float2 h2 = *(const float2*)(H + (size_t)s2.x*HID + lane*2);
    float2 h3 = *(const float2*)(H + (size_t)s3.x*HID + lane*2);
    float w0 = __int_as_float(s0.y), w1 = __int_as_float(s1.y);
    float w2 = __int_as_float(s2.y), w3 = __int_as_float(s3.y);
    a0 += w0*h0.x + w1*h1.x + w2*h2.x + w3*h3.x;
    a1 += w0*h0.y + w1*h1.y + w2*h2.y + w3*h3.y;
  }
  for (; j < cnt; j++){
    int2 sl = slots[st + j];
    float w = __int_as_float(sl.y);
    float2 hv = *(const float2*)(H + (size_t)sl.x*HID + lane*2);
    a0 += w*hv.x; a1 += w*hv.y;
  }
  float2 b = *(const float2*)(bias + lane*2);
  float2 o; o.x = a0 + b.x; o.y = a1 + b.y;
  *(float2*)(out + (size_t)n*HID + lane*2) = o;
}

extern "C" void kernel_launch(void* const* d_in, const int* in_sizes, int n_in,
                              void* d_out, int out_size, void* d_ws, size_t ws_size,
                              hipStream_t stream){
  const float* x  = (const float*)d_in[0];
  const int*   ei = (const int*)d_in[1];
  const float* Ws = (const float*)d_in[2];
  const float* bs = (const float*)d_in[3];
  const int N = in_sizes[0] / HID;
  const int E = in_sizes[1] / 2;
  const int L = in_sizes[2] / (HID*HID);
  const int* src = ei;        // edge_index[0]
  const int* dst = ei + E;    // edge_index[1]

  char* w = (char*)d_ws;
  int*   deg      = (int*)w;   w += (size_t)N*4;
  int*   fill     = (int*)w;   w += (size_t)N*4;
  int*   cursor   = (int*)w;   w += 16;
  size_t zbytes = (size_t)(w - (char*)d_ws);       // deg + fill + cursor must be zeroed
  float* dinv     = (float*)w; w += (size_t)N*4;
  int*   rowstart = (int*)w;   w += (size_t)N*4;
  int2*  slots    = (int2*)w;  w += (size_t)E*8;
  float* h        = (float*)w; w += (size_t)N*HID*4;

  hipMemsetAsync(d_ws, 0, zbytes, stream);

  int gE = (E + 255)/256, gN = (N + 255)/256;
  k_count_deg<<<gE, 256, 0, stream>>>(dst, deg, E);
  k_alloc   <<<gN, 256, 0, stream>>>(deg, rowstart, dinv, cursor, N);
  k_fill    <<<gE, 256, 0, stream>>>(src, dst, dinv, rowstart, fill, slots, E);

  const float* xin = x;
  float* out = (float*)d_out;
  for (int l = 0; l < L; l++){
    k_gemm<<<(N + 31)/32, 256, 0, stream>>>(xin, Ws + (size_t)l*HID*HID, h, N);
    k_agg <<<(N + 3)/4,  256, 0, stream>>>(h, slots, rowstart, deg, bs + (size_t)l*HID, out, N);
    xin = out;
  }
}

// Round 4
// 450.617 us; speedup vs baseline: 6.2570x; 1.1944x over previous
//
#include <hip/hip_runtime.h>

#define HID 128

static __device__ __forceinline__ unsigned short f2bf(float f){
  unsigned u = __float_as_uint(f);
  unsigned r = (u + 0x7FFF + ((u >> 16) & 1)) >> 16;   // RNE
  return (unsigned short)r;
}
static __device__ __forceinline__ float bf2f_lo(unsigned u){ return __uint_as_float(u << 16); }
static __device__ __forceinline__ float bf2f_hi(unsigned u){ return __uint_as_float(u & 0xFFFF0000u); }

__global__ __launch_bounds__(256) void k_count_deg(const int* __restrict__ dst, int* __restrict__ deg, int E){
  int e = blockIdx.x*256 + threadIdx.x;
  if (e < E) atomicAdd(&deg[dst[e]], 1);
}

// Per-block inclusive scan of deg, one atomic bump of a global cursor per block.
// Also emits dinv (fused).
__global__ __launch_bounds__(256) void k_alloc(const int* __restrict__ deg, int* __restrict__ rowstart,
                                               float* __restrict__ dinv, int* __restrict__ cursor, int N){
  __shared__ int sm[256];
  __shared__ int sbase;
  int t = threadIdx.x;
  int n = blockIdx.x*256 + t;
  int d = (n < N) ? deg[n] : 0;
  sm[t] = d;
  __syncthreads();
  for (int off = 1; off < 256; off <<= 1){
    int v = (t >= off) ? sm[t-off] : 0;
    __syncthreads();
    sm[t] += v;
    __syncthreads();
  }
  if (t == 255) sbase = atomicAdd(cursor, sm[255]);
  __syncthreads();
  if (n < N){
    rowstart[n] = sbase + sm[t] - d;
    dinv[n] = d > 0 ? rsqrtf((float)d) : 0.0f;
  }
}

__global__ __launch_bounds__(256) void k_fill(const int* __restrict__ src, const int* __restrict__ dst,
                                              const float* __restrict__ dinv, const int* __restrict__ rowstart,
                                              int* __restrict__ fill, int2* __restrict__ slots, int E){
  int e = blockIdx.x*256 + threadIdx.x;
  if (e >= E) return;
  int s = src[e], d = dst[e];
  int p = atomicAdd(&fill[d], 1);
  float w = dinv[s]*dinv[d];
  slots[rowstart[d] + p] = make_int2(s, __float_as_int(w));
}

// H[r] = X[r] @ W, H stored as bf16 (gather target only; halves agg traffic).
// W (64KB) in LDS, 32-row X tile in LDS, per-thread 4x4 register block.
// k-loop unroll BOUNDED to 2 (R1: full unroll -> 256 VGPR + 1.35GB spill traffic).
__global__ __launch_bounds__(256) void k_gemm(const float* __restrict__ X, const float* __restrict__ W,
                                              unsigned int* __restrict__ H2, int N){
  __shared__ float sW[HID*HID];   // 64 KB
  __shared__ float sX[32*HID];    // 16 KB
  int t = threadIdx.x;
  const float4* W4 = (const float4*)W;
  float4* sW4 = (float4*)sW;
#pragma unroll
  for (int i = 0; i < 16; i++) sW4[t + 256*i] = W4[t + 256*i];
  int row0 = blockIdx.x * 32;
  float4* sX4 = (float4*)sX;
#pragma unroll
  for (int i = 0; i < 4; i++){
    int idx = t + 256*i;                 // float4 index in tile; 32 per row
    int r = row0 + (idx >> 5);
    float4 v = make_float4(0.f,0.f,0.f,0.f);
    if (r < N) v = *(const float4*)(X + (size_t)r*HID + (size_t)(idx & 31)*4);
    sX4[idx] = v;
  }
  __syncthreads();
  int tx = t & 31, ty = t >> 5;
  float acc[4][4] = {};
  const float* xs = sX + ty*4*HID;
#pragma unroll 2
  for (int k = 0; k < HID; k += 4){
    float4 wv[4];
#pragma unroll
    for (int kk = 0; kk < 4; kk++) wv[kk] = *(const float4*)(sW + (size_t)(k+kk)*HID + tx*4);
#pragma unroll
    for (int r = 0; r < 4; r++){
      float4 xv = *(const float4*)(xs + r*HID + k);
      float xk[4] = {xv.x, xv.y, xv.z, xv.w};
#pragma unroll
      for (int kk = 0; kk < 4; kk++){
        acc[r][0] += xk[kk]*wv[kk].x;
        acc[r][1] += xk[kk]*wv[kk].y;
        acc[r][2] += xk[kk]*wv[kk].z;
        acc[r][3] += xk[kk]*wv[kk].w;
      }
    }
  }
#pragma unroll
  for (int r = 0; r < 4; r++){
    int row = row0 + ty*4 + r;
    if (row < N){
      uint2 p;
      p.x = (unsigned)f2bf(acc[r][0]) | ((unsigned)f2bf(acc[r][1]) << 16);
      p.y = (unsigned)f2bf(acc[r][2]) | ((unsigned)f2bf(acc[r][3]) << 16);
      *(uint2*)(H2 + (size_t)row*(HID/2) + tx*2) = p;
    }
  }
}

// One wave per node; lane holds one bf16x2 (2 cols) of the 128-wide row.
// Edge loop unrolled 8x: 8 independent slot loads + 8 independent row gathers
// in flight per wave (R2/R3: gather is latency-bound; accumulate in f32).
__global__ __launch_bounds__(256) void k_agg(const unsigned int* __restrict__ H2, const int2* __restrict__ slots,
                                             const int* __restrict__ rowstart, const int* __restrict__ deg,
                                             const float* __restrict__ bias, float* __restrict__ out, int N){
  int wid = threadIdx.x >> 6, lane = threadIdx.x & 63;
  int n = blockIdx.x*4 + wid;
  if (n >= N) return;
  int st = rowstart[n], cnt = deg[n];
  float a0 = 0.f, a1 = 0.f;
  int j = 0;
  for (; j + 8 <= cnt; j += 8){
    int2 sl[8];
#pragma unroll
    for (int q = 0; q < 8; q++) sl[q] = slots[st+j+q];
    unsigned hv[8];
#pragma unroll
    for (int q = 0; q < 8; q++) hv[q] = H2[(size_t)sl[q].x*(HID/2) + lane];
#pragma unroll
    for (int q = 0; q < 8; q++){
      float w = __int_as_float(sl[q].y);
      a0 += w*bf2f_lo(hv[q]);
      a1 += w*bf2f_hi(hv[q]);
    }
  }
  for (; j < cnt; j++){
    int2 sl = slots[st + j];
    float w = __int_as_float(sl.y);
    unsigned hv = H2[(size_t)sl.x*(HID/2) + lane];
    a0 += w*bf2f_lo(hv);
    a1 += w*bf2f_hi(hv);
  }
  float2 b = *(const float2*)(bias + lane*2);
  float2 o; o.x = a0 + b.x; o.y = a1 + b.y;
  *(float2*)(out + (size_t)n*HID + lane*2) = o;
}

extern "C" void kernel_launch(void* const* d_in, const int* in_sizes, int n_in,
                              void* d_out, int out_size, void* d_ws, size_t ws_size,
                              hipStream_t stream){
  const float* x  = (const float*)d_in[0];
  const int*   ei = (const int*)d_in[1];
  const float* Ws = (const float*)d_in[2];
  const float* bs = (const float*)d_in[3];
  const int N = in_sizes[0] / HID;
  const int E = in_sizes[1] / 2;
  const int L = in_sizes[2] / (HID*HID);
  const int* src = ei;        // edge_index[0]
  const int* dst = ei + E;    // edge_index[1]

  char* w = (char*)d_ws;
  int*   deg      = (int*)w;   w += (size_t)N*4;
  int*   fill     = (int*)w;   w += (size_t)N*4;
  int*   cursor   = (int*)w;   w += 16;
  size_t zbytes = (size_t)(w - (char*)d_ws);       // deg + fill + cursor must be zeroed
  float* dinv     = (float*)w; w += (size_t)N*4;
  int*   rowstart = (int*)w;   w += (size_t)N*4;
  int2*  slots    = (int2*)w;  w += (size_t)E*8;
  unsigned int* h2 = (unsigned int*)w; w += (size_t)N*(HID/2)*4;

  hipMemsetAsync(d_ws, 0, zbytes, stream);

  int gE = (E + 255)/256, gN = (N + 255)/256;
  k_count_deg<<<gE, 256, 0, stream>>>(dst, deg, E);
  k_alloc   <<<gN, 256, 0, stream>>>(deg, rowstart, dinv, cursor, N);
  k_fill    <<<gE, 256, 0, stream>>>(src, dst, dinv, rowstart, fill, slots, E);

  const float* xin = x;
  float* out = (float*)d_out;
  for (int l = 0; l < L; l++){
    k_gemm<<<(N + 31)/32, 256, 0, stream>>>(xin, Ws + (size_t)l*HID*HID, h2, N);
    k_agg <<<(N + 3)/4,  256, 0, stream>>>(h2, slots, rowstart, deg, bs + (size_t)l*HID, out, N);
    xin = out;
  }
}

// Round 6
// 407.901 us; speedup vs baseline: 6.9122x; 1.1047x over previous
//
#include <hip/hip_runtime.h>

#define HID 128
#define WFRAG (HID*HID)   // 16384 fragment elements per layer (was 8192 = R5 bug)

typedef __attribute__((ext_vector_type(8))) short bf16x8;
typedef __attribute__((ext_vector_type(4))) float f32x4;

static __device__ __forceinline__ unsigned short f2bf(float f){
  unsigned u = __float_as_uint(f);
  unsigned r = (u + 0x7FFF + ((u >> 16) & 1)) >> 16;   // RNE
  return (unsigned short)r;
}
static __device__ __forceinline__ float bf2f_lo(unsigned u){ return __uint_as_float(u << 16); }
static __device__ __forceinline__ float bf2f_hi(unsigned u){ return __uint_as_float(u & 0xFFFF0000u); }

static __device__ __forceinline__ unsigned cvtpk(float lo, float hi){
  unsigned r;
  asm volatile("v_cvt_pk_bf16_f32 %0, %1, %2" : "=v"(r) : "v"(lo), "v"(hi));
  return r;
}

__global__ __launch_bounds__(256) void k_count_deg(const int* __restrict__ dst, int* __restrict__ deg, int E){
  int e = blockIdx.x*256 + threadIdx.x;
  if (e < E) atomicAdd(&deg[dst[e]], 1);
}

// Per-block inclusive scan of deg + one global-cursor bump; emits dinv too.
__global__ __launch_bounds__(256) void k_alloc(const int* __restrict__ deg, int* __restrict__ rowstart,
                                               float* __restrict__ dinv, int* __restrict__ cursor, int N){
  __shared__ int sm[256];
  __shared__ int sbase;
  int t = threadIdx.x;
  int n = blockIdx.x*256 + t;
  int d = (n < N) ? deg[n] : 0;
  sm[t] = d;
  __syncthreads();
  for (int off = 1; off < 256; off <<= 1){
    int v = (t >= off) ? sm[t-off] : 0;
    __syncthreads();
    sm[t] += v;
    __syncthreads();
  }
  if (t == 255) sbase = atomicAdd(cursor, sm[255]);
  __syncthreads();
  if (n < N){
    rowstart[n] = sbase + sm[t] - d;
    dinv[n] = d > 0 ? rsqrtf((float)d) : 0.0f;
  }
}

__global__ __launch_bounds__(256) void k_fill(const int* __restrict__ src, const int* __restrict__ dst,
                                              const float* __restrict__ dinv, const int* __restrict__ rowstart,
                                              int* __restrict__ fill, int2* __restrict__ slots, int E){
  int e = blockIdx.x*256 + threadIdx.x;
  if (e >= E) return;
  int s = src[e], d = dst[e];
  int p = atomicAdd(&fill[d], 1);
  float w = dinv[s]*dinv[d];
  slots[rowstart[d] + p] = make_int2(s, __float_as_int(w));
}

// Decompose W (f32 [k][n]) into MFMA B-fragment-layout bf16 hi/lo tables.
// Frag layout (mfma_f32_16x16x32_bf16): B col=lane&15, k=8*(lane>>4)+j.
// Flattened: [(layer*8+nblk)*4+kstep][lane][j]  -> layer stride WFRAG=16384.
__global__ __launch_bounds__(256) void k_wprep(const float* __restrict__ Ws, unsigned short* __restrict__ Whi,
                                               unsigned short* __restrict__ Wlo){
  int layer = blockIdx.x;
  const float* W = Ws + (size_t)layer*HID*HID;
  for (int idx = threadIdx.x; idx < 2048; idx += 256){
    int lane = idx & 63, kstep = (idx>>6)&3, nblk = idx>>8;
    int col = 16*nblk + (lane&15);
    int k0  = 32*kstep + 8*(lane>>4);
    size_t obase = ((size_t)(layer*8 + nblk)*4 + kstep)*512 + (size_t)lane*8;
    for (int j = 0; j < 8; j++){
      float v = W[(size_t)(k0+j)*HID + col];
      unsigned short h = f2bf(v);
      float hf = __uint_as_float((unsigned)h << 16);
      Whi[obase+j] = h;
      Wlo[obase+j] = f2bf(v - hf);
    }
  }
}

// H = X @ W via split-precision bf16 MFMA (hi*hi + lo*hi + hi*lo ~ f32 accuracy).
// 32 rows x 128 cols per block; wave w owns cols [32w,32w+32). H stored bf16.
__global__ __launch_bounds__(256) void k_gemm_mfma(const float* __restrict__ X, const unsigned short* __restrict__ Whi,
                                                   const unsigned short* __restrict__ Wlo,
                                                   unsigned short* __restrict__ H2u, int N){
  int t = threadIdx.x, w = t>>6, l = t&63;
  int row0 = blockIdx.x*32;
  int lrow = l & 15, lk = (l>>4)*8;
  f32x4 acc[2][2] = {};
#pragma unroll 1
  for (int kstep = 0; kstep < 4; kstep++){
    bf16x8 ahi[2], alo[2];
#pragma unroll
    for (int m = 0; m < 2; m++){
      int row = row0 + 16*m + lrow;
      if (row >= N) row = N-1;                    // N%32==0 here; generic safety
      const float* ap = X + (size_t)row*HID + kstep*32 + lk;
      float4 a0 = *(const float4*)ap;
      float4 a1 = *(const float4*)(ap+4);
      int4 hh, ll;
      hh.x = cvtpk(a0.x, a0.y); hh.y = cvtpk(a0.z, a0.w);
      hh.z = cvtpk(a1.x, a1.y); hh.w = cvtpk(a1.z, a1.w);
      ll.x = cvtpk(a0.x - bf2f_lo(hh.x), a0.y - bf2f_hi(hh.x));
      ll.y = cvtpk(a0.z - bf2f_lo(hh.y), a0.w - bf2f_hi(hh.y));
      ll.z = cvtpk(a1.x - bf2f_lo(hh.z), a1.y - bf2f_hi(hh.z));
      ll.w = cvtpk(a1.z - bf2f_lo(hh.w), a1.w - bf2f_hi(hh.w));
      ahi[m] = *(bf16x8*)&hh;
      alo[m] = *(bf16x8*)&ll;
    }
    bf16x8 bhi[2], blo[2];
#pragma unroll
    for (int n = 0; n < 2; n++){
      size_t base = ((size_t)((2*w+n)*4 + kstep))*512 + (size_t)l*8;
      bhi[n] = *(const bf16x8*)(Whi + base);
      blo[n] = *(const bf16x8*)(Wlo + base);
    }
#pragma unroll
    for (int m = 0; m < 2; m++)
#pragma unroll
      for (int n = 0; n < 2; n++){
        acc[m][n] = __builtin_amdgcn_mfma_f32_16x16x32_bf16(ahi[m], bhi[n], acc[m][n], 0, 0, 0);
        acc[m][n] = __builtin_amdgcn_mfma_f32_16x16x32_bf16(alo[m], bhi[n], acc[m][n], 0, 0, 0);
        acc[m][n] = __builtin_amdgcn_mfma_f32_16x16x32_bf16(ahi[m], blo[n], acc[m][n], 0, 0, 0);
      }
  }
  // D: row=4*(lane>>4)+r, col=lane&15 (m89-verified)
#pragma unroll
  for (int m = 0; m < 2; m++)
#pragma unroll
    for (int r = 0; r < 4; r++){
      int row = row0 + 16*m + 4*(l>>4) + r;
      if (row < N){
#pragma unroll
        for (int n = 0; n < 2; n++){
          int col = 16*(2*w+n) + lrow;
          H2u[(size_t)row*HID + col] = f2bf(acc[m][n][r]);
        }
      }
    }
}

// One wave per node; lane holds one bf16x2 (2 cols). 8-deep gather pipeline.
__global__ __launch_bounds__(256) void k_agg(const unsigned int* __restrict__ H2, const int2* __restrict__ slots,
                                             const int* __restrict__ rowstart, const int* __restrict__ deg,
                                             const float* __restrict__ bias, float* __restrict__ out, int N){
  int wid = threadIdx.x >> 6, lane = threadIdx.x & 63;
  int n = blockIdx.x*4 + wid;
  if (n >= N) return;
  int st = rowstart[n], cnt = deg[n];
  float a0 = 0.f, a1 = 0.f;
  int j = 0;
  for (; j + 8 <= cnt; j += 8){
    int2 sl[8];
#pragma unroll
    for (int q = 0; q < 8; q++) sl[q] = slots[st+j+q];
    unsigned hv[8];
#pragma unroll
    for (int q = 0; q < 8; q++) hv[q] = H2[(size_t)sl[q].x*(HID/2) + lane];
#pragma unroll
    for (int q = 0; q < 8; q++){
      float w = __int_as_float(sl[q].y);
      a0 += w*bf2f_lo(hv[q]);
      a1 += w*bf2f_hi(hv[q]);
    }
  }
  for (; j < cnt; j++){
    int2 sl = slots[st + j];
    float w = __int_as_float(sl.y);
    unsigned hv = H2[(size_t)sl.x*(HID/2) + lane];
    a0 += w*bf2f_lo(hv);
    a1 += w*bf2f_hi(hv);
  }
  float2 b = *(const float2*)(bias + lane*2);
  float2 o; o.x = a0 + b.x; o.y = a1 + b.y;
  *(float2*)(out + (size_t)n*HID + lane*2) = o;
}

extern "C" void kernel_launch(void* const* d_in, const int* in_sizes, int n_in,
                              void* d_out, int out_size, void* d_ws, size_t ws_size,
                              hipStream_t stream){
  const float* x  = (const float*)d_in[0];
  const int*   ei = (const int*)d_in[1];
  const float* Ws = (const float*)d_in[2];
  const float* bs = (const float*)d_in[3];
  const int N = in_sizes[0] / HID;
  const int E = in_sizes[1] / 2;
  const int L = in_sizes[2] / (HID*HID);
  const int* src = ei;        // edge_index[0]
  const int* dst = ei + E;    // edge_index[1]

  char* w = (char*)d_ws;
  int*   deg      = (int*)w;   w += (size_t)N*4;
  int*   fill     = (int*)w;   w += (size_t)N*4;
  int*   cursor   = (int*)w;   w += 16;
  size_t zbytes = (size_t)(w - (char*)d_ws);       // deg + fill + cursor must be zeroed
  float* dinv     = (float*)w; w += (size_t)N*4;
  int*   rowstart = (int*)w;   w += (size_t)N*4;
  int2*  slots    = (int2*)w;  w += (size_t)E*8;
  unsigned short* h2u = (unsigned short*)w; w += (size_t)N*HID*2;
  unsigned short* whi = (unsigned short*)w; w += (size_t)L*WFRAG*2;
  unsigned short* wlo = (unsigned short*)w; w += (size_t)L*WFRAG*2;

  hipMemsetAsync(d_ws, 0, zbytes, stream);

  int gE = (E + 255)/256, gN = (N + 255)/256;
  k_count_deg<<<gE, 256, 0, stream>>>(dst, deg, E);
  k_alloc   <<<gN, 256, 0, stream>>>(deg, rowstart, dinv, cursor, N);
  k_wprep   <<<L,  256, 0, stream>>>(Ws, whi, wlo);
  k_fill    <<<gE, 256, 0, stream>>>(src, dst, dinv, rowstart, fill, slots, E);

  const float* xin = x;
  float* out = (float*)d_out;
  for (int l = 0; l < L; l++){
    k_gemm_mfma<<<(N + 31)/32, 256, 0, stream>>>(xin, whi + (size_t)l*WFRAG, wlo + (size_t)l*WFRAG, h2u, N);
    k_agg<<<(N + 3)/4, 256, 0, stream>>>((const unsigned int*)h2u, slots, rowstart, deg,
                                         bs + (size_t)l*HID, out, N);
    xin = out;
  }
}